// Round 14
// baseline (196.427 us; speedup 1.0000x reference)
//
#include <hip/hip_runtime.h>

typedef unsigned short u16;
typedef __fp16 halfx2 __attribute__((ext_vector_type(2)));
typedef __fp16 halfx8 __attribute__((ext_vector_type(8)));
typedef float floatx4 __attribute__((ext_vector_type(4)));
typedef unsigned short u16x4 __attribute__((ext_vector_type(4)));
typedef unsigned short u16x8 __attribute__((ext_vector_type(8)));

#define D_MODEL 768
#define NH 12
#define DH 64
#define SEQ 2048
#define BATCH 2
#define MTOK 4096            // BATCH*SEQ
#define DQKV 2304

__device__ __forceinline__ u16 f2h(float f) {
    __fp16 h = (__fp16)f;
    return __builtin_bit_cast(u16, h);
}

__device__ __forceinline__ void gload_lds16(const void* g, void* l) {
    __builtin_amdgcn_global_load_lds(
        (const __attribute__((address_space(1))) void*)g,
        (__attribute__((address_space(3))) void*)l, 16, 0, 0);
}

// ---------------- prep: Wq/Wk/Wv transposes -> f16 [n][k] (432 blocks) ----------------
// Wo's transpose is folded into attn_kernel's prologue (no ordering needed:
// WoT is consumed only by gemm_out after a kernel boundary).

__global__ __launch_bounds__(256) void wprep_kernel(const float* __restrict__ Wq, const float* __restrict__ Wk,
                                                    const float* __restrict__ Wv, u16* __restrict__ WqkvT) {
    __shared__ u16 t[64][72];
    int bid = blockIdx.x;
    int tid = threadIdx.x;
    int z = bid / 144;
    int t2 = bid % 144;
    int k0 = (t2 / 12) * 64, n0 = (t2 % 12) * 64;
    const float* W = (z == 0) ? Wq : (z == 1) ? Wk : Wv;
    u16* dst = WqkvT + (size_t)z * 768 * 768;
#pragma unroll
    for (int p = 0; p < 16; ++p) {
        int idx = p * 256 + tid;
        int kr = idx >> 6, nc = idx & 63;
        t[kr][nc] = f2h(W[(size_t)(k0 + kr) * 768 + n0 + nc]);
    }
    __syncthreads();
#pragma unroll
    for (int p = 0; p < 16; ++p) {
        int idx = p * 256 + tid;
        int nr = idx >> 6, kc = idx & 63;
        dst[(size_t)(n0 + nr) * 768 + k0 + kc] = t[kc][nr];
    }
}

// ---------------- QKV GEMM, A staged from fp32 x with fused cvt (R11 verbatim) ----------------
// 64x128 tile (1152 blocks), BK=64. Epilogue: Q -> qP[bh][s][64] pre-scaled by
// 0.125*log2e, K -> kP[bh][s][64], V -> vT[bh][d][s].

__global__ __launch_bounds__(256) void gemm_qkv(const float* __restrict__ x, const u16* __restrict__ Bt,
                                                const float* __restrict__ bq, const float* __restrict__ bk,
                                                const float* __restrict__ bv,
                                                u16* __restrict__ qP, u16* __restrict__ kP,
                                                u16* __restrict__ vTout) {
    const int tid = threadIdx.x;
    const int wid = tid >> 6;
    const int lane = tid & 63;
    const int qd = lane >> 4;
    const int l15 = lane & 15;

    const int tn = blockIdx.x * 128;   // 18 n-tiles
    const int tm = blockIdx.y * 64;    // 64 m-tiles
    const int wm = (wid >> 1) * 32;
    const int wn = (wid & 1) * 64;

    __shared__ alignas(16) u16 As[64 * 64];    // 8 KB
    __shared__ alignas(16) u16 Bs[128 * 64];   // 16 KB

    floatx4 acc[2][4];
#pragma unroll
    for (int i = 0; i < 2; ++i)
#pragma unroll
        for (int j = 0; j < 4; ++j) acc[i][j] = (floatx4)(0.0f);

    int ar[2], abl[2];
#pragma unroll
    for (int rd = 0; rd < 2; ++rd) {
        int s = rd * 256 + tid;
        ar[rd] = s >> 3;
        abl[rd] = (s & 7) ^ (ar[rd] & 7);
    }
    const u16* Bg[4];
#pragma unroll
    for (int rd = 0; rd < 4; ++rd) {
        int s = rd * 256 + tid;
        int r = s >> 3, bl = (s & 7) ^ (r & 7);
        Bg[rd] = Bt + (size_t)(tn + r) * 768 + bl * 8;
    }

    for (int kb = 0; kb < 768; kb += 64) {
        __syncthreads();
#pragma unroll
        for (int rd = 0; rd < 2; ++rd) {
            const float* src = x + (size_t)(tm + ar[rd]) * 768 + kb + abl[rd] * 8;
            float4 v0 = *(const float4*)src;
            float4 v1 = *(const float4*)(src + 4);
            union { u16x8 u; halfx2 h[4]; } pk;
            pk.h[0] = __builtin_amdgcn_cvt_pkrtz(v0.x, v0.y);
            pk.h[1] = __builtin_amdgcn_cvt_pkrtz(v0.z, v0.w);
            pk.h[2] = __builtin_amdgcn_cvt_pkrtz(v1.x, v1.y);
            pk.h[3] = __builtin_amdgcn_cvt_pkrtz(v1.z, v1.w);
            *(u16x8*)(As + (size_t)(rd * 256 + tid) * 8) = pk.u;
        }
#pragma unroll
        for (int rd = 0; rd < 4; ++rd)
            gload_lds16(Bg[rd] + kb, Bs + (size_t)(rd * 256 + tid) * 8);
        __syncthreads();

#pragma unroll
        for (int ks = 0; ks < 2; ++ks) {
            halfx8 af[2], bf[4];
#pragma unroll
            for (int i = 0; i < 2; ++i) {
                int r = wm + i * 16 + l15;
                af[i] = *(const halfx8*)(As + r * 64 + (((ks * 4 + qd) ^ (r & 7)) * 8));
            }
#pragma unroll
            for (int j = 0; j < 4; ++j) {
                int r2 = wn + j * 16 + l15;
                bf[j] = *(const halfx8*)(Bs + r2 * 64 + (((ks * 4 + qd) ^ (r2 & 7)) * 8));
            }
#pragma unroll
            for (int i = 0; i < 2; ++i)
#pragma unroll
                for (int j = 0; j < 4; ++j)
                    acc[i][j] = __builtin_amdgcn_mfma_f32_16x16x32_f16(af[i], bf[j], acc[i][j], 0, 0, 0);
        }
    }

    const float cscale = 0.125f * 1.44269504088896340736f;
    const int rgn = (tn < 768) ? 0 : (tn < 1536) ? 1 : 2;   // block-uniform
    const float* bsrc = (rgn == 0) ? bq : (rgn == 1) ? bk : bv;
#pragma unroll
    for (int j = 0; j < 4; ++j) {
        int col = tn + wn + j * 16 + l15;
        int cl = col - rgn * 768;
        float bvv = bsrc[cl];
        int h = cl >> 6, d = cl & 63;
#pragma unroll
        for (int i = 0; i < 2; ++i) {
            int row0 = tm + wm + i * 16 + qd * 4;
            int b = row0 >> 11, s0 = row0 & 2047;
            u16x4 pk;
#pragma unroll
            for (int r = 0; r < 4; ++r) {
                float v = acc[i][j][r] + bvv;
                if (rgn == 0) v *= cscale;
                pk[r] = f2h(v);
            }
            if (rgn == 2) {
                *(u16x4*)(vTout + ((size_t)(b * NH + h) * 64 + d) * SEQ + s0) = pk;
            } else {
                u16* dst = (rgn == 0) ? qP : kP;
#pragma unroll
                for (int r = 0; r < 4; ++r)
                    dst[((size_t)(b * NH + h) * SEQ + s0 + r) * DH + d] = pk[r];
            }
        }
    }
}

// ---------------- software-pipelined attention (R11 verbatim) + Wo-transpose prologue ----------------
// grid = (24 bh, 32 q-tiles). First 144 blocks each transpose one 64x64 Wo
// tile before their attn work (pure independent work, no sync: gemm_out reads
// WoT only after the kernel boundary). Attn phase identical to R11 (verified
// 61 us): sc(t) from last iter; per iter loads(t+1) -> exp(t) -> QK(t+1)
// [MFMA overlaps VALU] -> P LDS -> ones+PV(t). launch_bounds(256,2).

__global__ __launch_bounds__(256, 2) void attn_kernel(const u16* __restrict__ qP, const u16* __restrict__ kP,
                                                      const u16* __restrict__ vT, u16* __restrict__ attn,
                                                      const float* __restrict__ Wo, u16* __restrict__ WoT) {
    const int tid = threadIdx.x;
    const int wid = tid >> 6;
    const int lane = tid & 63;
    const int qd = lane >> 4;
    const int l15 = lane & 15;

    const int bh = blockIdx.x;
    const int b = bh / NH, h = bh % NH;
    const int q0 = blockIdx.y * 64;

    __shared__ alignas(16) u16 smem[9216];   // 18 KB: per wave [64][36] P / t72 staging
    u16* ps = smem + wid * 2304;

    // ---- prologue: Wo transpose, 144 tiles on the first 144 blocks ----
    {
        int flat = bh + 24 * blockIdx.y;
        if (flat < 144) {
            u16(*t72)[72] = (u16(*)[72])smem;
            int k0 = (flat / 12) * 64, n0 = (flat % 12) * 64;
#pragma unroll
            for (int p = 0; p < 16; ++p) {
                int idx = p * 256 + tid;
                int kr = idx >> 6, nc = idx & 63;
                t72[kr][nc] = f2h(Wo[(size_t)(k0 + kr) * 768 + n0 + nc]);
            }
            __syncthreads();
#pragma unroll
            for (int p = 0; p < 16; ++p) {
                int idx = p * 256 + tid;
                int nr = idx >> 6, kc = idx & 63;
                WoT[(size_t)(n0 + nr) * 768 + k0 + kc] = t72[kc][nr];
            }
            __syncthreads();
        }
    }

    halfx8 aq[4][2];
#pragma unroll
    for (int jn = 0; jn < 4; ++jn)
#pragma unroll
        for (int ks = 0; ks < 2; ++ks)
            aq[jn][ks] = *(const halfx8*)(qP + (size_t)(bh * SEQ + q0 + jn * 16 + l15) * DH + ks * 32 + qd * 8);

    halfx8 ones;
#pragma unroll
    for (int j = 0; j < 8; ++j) ones[j] = (__fp16)1.0f;

    floatx4 o[4][4];
#pragma unroll
    for (int ip = 0; ip < 4; ++ip)
#pragma unroll
        for (int jn = 0; jn < 4; ++jn) o[ip][jn] = (floatx4)(0.0f);
    floatx4 lsum[4];
#pragma unroll
    for (int jn = 0; jn < 4; ++jn) lsum[jn] = (floatx4)(0.0f);

    const u16* kbase = kP + (size_t)(bh * SEQ + wid * 32 + l15) * DH + qd * 8;
    const u16* vbase = vT + (size_t)(bh * 64 + l15) * SEQ + wid * 32 + qd * 8;

    // prologue: load K(0), V(0); compute sc = QK(0)
    halfx8 akn[2][2], avc[4];
#pragma unroll
    for (int mi = 0; mi < 2; ++mi)
#pragma unroll
        for (int ks = 0; ks < 2; ++ks)
            akn[mi][ks] = *(const halfx8*)(kbase + (size_t)(mi * 16) * DH + ks * 32);
#pragma unroll
    for (int ip = 0; ip < 4; ++ip)
        avc[ip] = *(const halfx8*)(vbase + (size_t)(ip * 16) * SEQ);

    floatx4 sc[2][4];
#pragma unroll
    for (int mi = 0; mi < 2; ++mi)
#pragma unroll
        for (int jn = 0; jn < 4; ++jn) sc[mi][jn] = (floatx4)(0.0f);
#pragma unroll
    for (int ks = 0; ks < 2; ++ks)
#pragma unroll
        for (int mi = 0; mi < 2; ++mi)
#pragma unroll
            for (int jn = 0; jn < 4; ++jn)
                sc[mi][jn] = __builtin_amdgcn_mfma_f32_16x16x32_f16(akn[mi][ks], aq[jn][ks], sc[mi][jn], 0, 0, 0);

    for (int kt = 0; kt < 16; ++kt) {
        int ktn = (kt + 1) & 15;
        halfx8 avn[4];
#pragma unroll
        for (int mi = 0; mi < 2; ++mi)
#pragma unroll
            for (int ks = 0; ks < 2; ++ks)
                akn[mi][ks] = *(const halfx8*)(kbase + (size_t)(ktn * 128 + mi * 16) * DH + ks * 32);
#pragma unroll
        for (int ip = 0; ip < 4; ++ip)
            avn[ip] = *(const halfx8*)(vbase + (size_t)(ip * 16) * SEQ + ktn * 128);

        // exp(t) from sc (computed last iteration -> no MFMA hazard)
#pragma unroll
        for (int mi = 0; mi < 2; ++mi)
#pragma unroll
            for (int jn = 0; jn < 4; ++jn) {
                float p0 = __builtin_amdgcn_exp2f(sc[mi][jn][0]);
                float p1 = __builtin_amdgcn_exp2f(sc[mi][jn][1]);
                float p2 = __builtin_amdgcn_exp2f(sc[mi][jn][2]);
                float p3 = __builtin_amdgcn_exp2f(sc[mi][jn][3]);
                union { u16x4 u; halfx2 h[2]; } pk;
                pk.h[0] = __builtin_amdgcn_cvt_pkrtz(p0, p1);
                pk.h[1] = __builtin_amdgcn_cvt_pkrtz(p2, p3);
                *(u16x4*)(ps + (jn * 16 + l15) * 36 + mi * 16 + qd * 4) = pk.u;
            }

        // QK(t+1) on the MFMA pipe (overlaps exp/pack VALU)
        floatx4 scn[2][4];
#pragma unroll
        for (int mi = 0; mi < 2; ++mi)
#pragma unroll
            for (int jn = 0; jn < 4; ++jn) scn[mi][jn] = (floatx4)(0.0f);
#pragma unroll
        for (int ks = 0; ks < 2; ++ks)
#pragma unroll
            for (int mi = 0; mi < 2; ++mi)
#pragma unroll
                for (int jn = 0; jn < 4; ++jn)
                    scn[mi][jn] = __builtin_amdgcn_mfma_f32_16x16x32_f16(akn[mi][ks], aq[jn][ks], scn[mi][jn], 0, 0, 0);

        // P(t) fragments (same-wave DS write->read ordering)
        halfx8 bp[4];
#pragma unroll
        for (int jn = 0; jn < 4; ++jn) {
            union { halfx8 h8; u16x4 u4[2]; } bpu;
            bpu.u4[0] = *(const u16x4*)(ps + (jn * 16 + l15) * 36 + qd * 8);
            bpu.u4[1] = *(const u16x4*)(ps + (jn * 16 + l15) * 36 + qd * 8 + 4);
            bp[jn] = bpu.h8;
        }

#pragma unroll
        for (int jn = 0; jn < 4; ++jn)
            lsum[jn] = __builtin_amdgcn_mfma_f32_16x16x32_f16(ones, bp[jn], lsum[jn], 0, 0, 0);
#pragma unroll
        for (int ip = 0; ip < 4; ++ip)
#pragma unroll
            for (int jn = 0; jn < 4; ++jn)
                o[ip][jn] = __builtin_amdgcn_mfma_f32_16x16x32_f16(avc[ip], bp[jn], o[ip][jn], 0, 0, 0);

#pragma unroll
        for (int ip = 0; ip < 4; ++ip) avc[ip] = avn[ip];
#pragma unroll
        for (int mi = 0; mi < 2; ++mi)
#pragma unroll
            for (int jn = 0; jn < 4; ++jn) sc[mi][jn] = scn[mi][jn];
    }

    // ---- cross-wave sum through LDS (aliases P region; P is dead) ----
    float* Oacc = (float*)smem;                  // [64][68] fp32
    float* la = (float*)smem + 4352;             // [64]

    __syncthreads();
    if (wid == 0) {
#pragma unroll
        for (int jn = 0; jn < 4; ++jn) {
            int q = jn * 16 + l15;
#pragma unroll
            for (int ip = 0; ip < 4; ++ip)
                *(floatx4*)(Oacc + q * 68 + ip * 16 + qd * 4) = o[ip][jn];
            if (qd == 0) la[q] = lsum[jn][0];
        }
    }
    for (int w = 1; w < 4; ++w) {
        __syncthreads();
        if (wid == w) {
#pragma unroll
            for (int jn = 0; jn < 4; ++jn) {
                int q = jn * 16 + l15;
#pragma unroll
                for (int ip = 0; ip < 4; ++ip) {
                    float* p = Oacc + q * 68 + ip * 16 + qd * 4;
                    *(floatx4*)p = *(floatx4*)p + o[ip][jn];
                }
                if (qd == 0) la[q] += lsum[jn][0];
            }
        }
    }
    __syncthreads();

    {
        int q = tid >> 2, d0 = (tid & 3) * 16;
        float inv = __builtin_amdgcn_rcpf(la[q]);
        const float* op = Oacc + q * 68 + d0;
        u16x8 pk0, pk1;
#pragma unroll
        for (int r = 0; r < 8; ++r) pk0[r] = f2h(op[r] * inv);
#pragma unroll
        for (int r = 0; r < 8; ++r) pk1[r] = f2h(op[8 + r] * inv);
        u16* dst = attn + (size_t)(b * SEQ + q0 + q) * D_MODEL + h * DH + d0;
        *(u16x8*)dst = pk0;
        *(u16x8*)(dst + 8) = pk1;
    }
}

// ---------------- out GEMM: C[4096][768] = A * WoT^T + bias (fp32 out) ----------------
// 64x64 tile (768 blocks, 3/CU), BK=64, 4 waves each 32x32.

__global__ __launch_bounds__(256) void gemm_out(const u16* __restrict__ A, const u16* __restrict__ Bt,
                                                const float* __restrict__ bias, float* __restrict__ Cout) {
    const int tid = threadIdx.x;
    const int wid = tid >> 6;
    const int lane = tid & 63;
    const int qd = lane >> 4;
    const int l15 = lane & 15;

    const int tn = blockIdx.x * 64;
    const int tm = blockIdx.y * 64;
    const int wm = (wid >> 1) * 32;
    const int wn = (wid & 1) * 32;

    __shared__ alignas(16) u16 As[64 * 64];
    __shared__ alignas(16) u16 Bs[64 * 64];

    floatx4 acc[2][2];
#pragma unroll
    for (int i = 0; i < 2; ++i)
#pragma unroll
        for (int j = 0; j < 2; ++j) acc[i][j] = (floatx4)(0.0f);

    const u16* Ag[2];
    const u16* Bg[2];
#pragma unroll
    for (int rd = 0; rd < 2; ++rd) {
        int s = rd * 256 + tid;
        int r = s >> 3, bl = (s & 7) ^ (r & 7);
        Ag[rd] = A + (size_t)(tm + r) * 768 + bl * 8;
        Bg[rd] = Bt + (size_t)(tn + r) * 768 + bl * 8;
    }

    for (int kb = 0; kb < 768; kb += 64) {
        __syncthreads();
#pragma unroll
        for (int rd = 0; rd < 2; ++rd) {
            gload_lds16(Ag[rd] + kb, As + (size_t)(rd * 256 + tid) * 8);
            gload_lds16(Bg[rd] + kb, Bs + (size_t)(rd * 256 + tid) * 8);
        }
        __syncthreads();

#pragma unroll
        for (int ks = 0; ks < 2; ++ks) {
            halfx8 af[2], bf[2];
#pragma unroll
            for (int i = 0; i < 2; ++i) {
                int r = wm + i * 16 + l15;
                af[i] = *(const halfx8*)(As + r * 64 + (((ks * 4 + qd) ^ (r & 7)) * 8));
                int r2 = wn + i * 16 + l15;
                bf[i] = *(const halfx8*)(Bs + r2 * 64 + (((ks * 4 + qd) ^ (r2 & 7)) * 8));
            }
#pragma unroll
            for (int i = 0; i < 2; ++i)
#pragma unroll
                for (int j = 0; j < 2; ++j)
                    acc[i][j] = __builtin_amdgcn_mfma_f32_16x16x32_f16(af[i], bf[j], acc[i][j], 0, 0, 0);
        }
    }

#pragma unroll
    for (int j = 0; j < 2; ++j) {
        int col = tn + wn + j * 16 + l15;
        float bv = bias[col];
#pragma unroll
        for (int i = 0; i < 2; ++i) {
            int row0 = tm + wm + i * 16 + qd * 4;
#pragma unroll
            for (int r = 0; r < 4; ++r)
                Cout[(size_t)(row0 + r) * 768 + col] = acc[i][j][r] + bv;
        }
    }
}

// ---------------- launch ----------------

extern "C" void kernel_launch(void* const* d_in, const int* in_sizes, int n_in,
                              void* d_out, int out_size, void* d_ws, size_t ws_size,
                              hipStream_t stream) {
    const float* x  = (const float*)d_in[0];
    const float* Wq = (const float*)d_in[1];
    const float* bq = (const float*)d_in[2];
    const float* Wk = (const float*)d_in[3];
    const float* bk = (const float*)d_in[4];
    const float* Wv = (const float*)d_in[5];
    const float* bv = (const float*)d_in[6];
    const float* Wo = (const float*)d_in[7];
    const float* bo = (const float*)d_in[8];

    char* ws = (char*)d_ws;
    size_t off = 0;
    auto take = [&](size_t bytes) -> char* {
        char* p = ws + off;
        off += (bytes + 255) & ~(size_t)255;
        return p;
    };
    u16* WqkvT = (u16*)take((size_t)DQKV * D_MODEL * 2);
    u16* WoT   = (u16*)take((size_t)D_MODEL * D_MODEL * 2);
    u16* qP    = (u16*)take((size_t)MTOK * D_MODEL * 2);
    u16* kP    = (u16*)take((size_t)MTOK * D_MODEL * 2);
    u16* vTb   = (u16*)take((size_t)BATCH * NH * DH * SEQ * 2);
    u16* attn  = (u16*)take((size_t)MTOK * D_MODEL * 2);

    wprep_kernel<<<432, 256, 0, stream>>>(Wq, Wk, Wv, WqkvT);
    gemm_qkv<<<dim3(DQKV / 128, MTOK / 64), 256, 0, stream>>>(x, WqkvT, bq, bk, bv, qP, kP, vTb);
    attn_kernel<<<dim3(BATCH * NH, SEQ / 64), 256, 0, stream>>>(qP, kP, vTb, attn, Wo, WoT);
    gemm_out<<<dim3(D_MODEL / 64, MTOK / 64), 256, 0, stream>>>(attn, WoT, bo, (float*)d_out);
}

// Round 15
// 179.062 us; speedup vs baseline: 1.0970x; 1.0970x over previous
//
#include <hip/hip_runtime.h>

typedef unsigned short u16;
typedef __fp16 halfx2 __attribute__((ext_vector_type(2)));
typedef __fp16 halfx8 __attribute__((ext_vector_type(8)));
typedef float floatx4 __attribute__((ext_vector_type(4)));
typedef unsigned short u16x4 __attribute__((ext_vector_type(4)));
typedef unsigned short u16x8 __attribute__((ext_vector_type(8)));

#define D_MODEL 768
#define NH 12
#define DH 64
#define SEQ 2048
#define BATCH 2
#define MTOK 4096            // BATCH*SEQ
#define DQKV 2304

__device__ __forceinline__ u16 f2h(float f) {
    __fp16 h = (__fp16)f;
    return __builtin_bit_cast(u16, h);
}

__device__ __forceinline__ void gload_lds16(const void* g, void* l) {
    __builtin_amdgcn_global_load_lds(
        (const __attribute__((address_space(1))) void*)g,
        (__attribute__((address_space(3))) void*)l, 16, 0, 0);
}

// ---------------- prep: W transposes -> f16 [n][k] (576 blocks) ----------------

__global__ __launch_bounds__(256) void wprep_kernel(const float* __restrict__ Wq, const float* __restrict__ Wk,
                                                    const float* __restrict__ Wv, const float* __restrict__ Wo,
                                                    u16* __restrict__ WqkvT, u16* __restrict__ WoT) {
    __shared__ u16 t[64][72];
    int bid = blockIdx.x;
    int tid = threadIdx.x;
    int z = bid / 144;
    int t2 = bid % 144;
    int k0 = (t2 / 12) * 64, n0 = (t2 % 12) * 64;
    const float* W = (z == 0) ? Wq : (z == 1) ? Wk : (z == 2) ? Wv : Wo;
    u16* dst = (z < 3) ? (WqkvT + (size_t)z * 768 * 768) : WoT;
#pragma unroll
    for (int p = 0; p < 16; ++p) {
        int idx = p * 256 + tid;
        int kr = idx >> 6, nc = idx & 63;
        t[kr][nc] = f2h(W[(size_t)(k0 + kr) * 768 + n0 + nc]);
    }
    __syncthreads();
#pragma unroll
    for (int p = 0; p < 16; ++p) {
        int idx = p * 256 + tid;
        int nr = idx >> 6, kc = idx & 63;
        dst[(size_t)(n0 + nr) * 768 + k0 + kc] = t[kc][nr];
    }
}

// ---------------- QKV GEMM, A staged from fp32 x with fused cvt ----------------
// 64x128 tile (1152 blocks), BK=64. Epilogue: Q -> qP[bh][s][64] pre-scaled by
// 0.125*log2e, K -> kP[bh][s][64], V -> vT[bh][d][s].

__global__ __launch_bounds__(256) void gemm_qkv(const float* __restrict__ x, const u16* __restrict__ Bt,
                                                const float* __restrict__ bq, const float* __restrict__ bk,
                                                const float* __restrict__ bv,
                                                u16* __restrict__ qP, u16* __restrict__ kP,
                                                u16* __restrict__ vTout) {
    const int tid = threadIdx.x;
    const int wid = tid >> 6;
    const int lane = tid & 63;
    const int qd = lane >> 4;
    const int l15 = lane & 15;

    const int tn = blockIdx.x * 128;   // 18 n-tiles
    const int tm = blockIdx.y * 64;    // 64 m-tiles
    const int wm = (wid >> 1) * 32;
    const int wn = (wid & 1) * 64;

    __shared__ alignas(16) u16 As[64 * 64];    // 8 KB
    __shared__ alignas(16) u16 Bs[128 * 64];   // 16 KB

    floatx4 acc[2][4];
#pragma unroll
    for (int i = 0; i < 2; ++i)
#pragma unroll
        for (int j = 0; j < 4; ++j) acc[i][j] = (floatx4)(0.0f);

    int ar[2], abl[2];
#pragma unroll
    for (int rd = 0; rd < 2; ++rd) {
        int s = rd * 256 + tid;
        ar[rd] = s >> 3;
        abl[rd] = (s & 7) ^ (ar[rd] & 7);
    }
    const u16* Bg[4];
#pragma unroll
    for (int rd = 0; rd < 4; ++rd) {
        int s = rd * 256 + tid;
        int r = s >> 3, bl = (s & 7) ^ (r & 7);
        Bg[rd] = Bt + (size_t)(tn + r) * 768 + bl * 8;
    }

    for (int kb = 0; kb < 768; kb += 64) {
        __syncthreads();
#pragma unroll
        for (int rd = 0; rd < 2; ++rd) {
            const float* src = x + (size_t)(tm + ar[rd]) * 768 + kb + abl[rd] * 8;
            float4 v0 = *(const float4*)src;
            float4 v1 = *(const float4*)(src + 4);
            union { u16x8 u; halfx2 h[4]; } pk;
            pk.h[0] = __builtin_amdgcn_cvt_pkrtz(v0.x, v0.y);
            pk.h[1] = __builtin_amdgcn_cvt_pkrtz(v0.z, v0.w);
            pk.h[2] = __builtin_amdgcn_cvt_pkrtz(v1.x, v1.y);
            pk.h[3] = __builtin_amdgcn_cvt_pkrtz(v1.z, v1.w);
            *(u16x8*)(As + (size_t)(rd * 256 + tid) * 8) = pk.u;
        }
#pragma unroll
        for (int rd = 0; rd < 4; ++rd)
            gload_lds16(Bg[rd] + kb, Bs + (size_t)(rd * 256 + tid) * 8);
        __syncthreads();

#pragma unroll
        for (int ks = 0; ks < 2; ++ks) {
            halfx8 af[2], bf[4];
#pragma unroll
            for (int i = 0; i < 2; ++i) {
                int r = wm + i * 16 + l15;
                af[i] = *(const halfx8*)(As + r * 64 + (((ks * 4 + qd) ^ (r & 7)) * 8));
            }
#pragma unroll
            for (int j = 0; j < 4; ++j) {
                int r2 = wn + j * 16 + l15;
                bf[j] = *(const halfx8*)(Bs + r2 * 64 + (((ks * 4 + qd) ^ (r2 & 7)) * 8));
            }
#pragma unroll
            for (int i = 0; i < 2; ++i)
#pragma unroll
                for (int j = 0; j < 4; ++j)
                    acc[i][j] = __builtin_amdgcn_mfma_f32_16x16x32_f16(af[i], bf[j], acc[i][j], 0, 0, 0);
        }
    }

    const float cscale = 0.125f * 1.44269504088896340736f;
    const int rgn = (tn < 768) ? 0 : (tn < 1536) ? 1 : 2;   // block-uniform
    const float* bsrc = (rgn == 0) ? bq : (rgn == 1) ? bk : bv;
#pragma unroll
    for (int j = 0; j < 4; ++j) {
        int col = tn + wn + j * 16 + l15;
        int cl = col - rgn * 768;
        float bvv = bsrc[cl];
        int h = cl >> 6, d = cl & 63;
#pragma unroll
        for (int i = 0; i < 2; ++i) {
            int row0 = tm + wm + i * 16 + qd * 4;
            int b = row0 >> 11, s0 = row0 & 2047;
            u16x4 pk;
#pragma unroll
            for (int r = 0; r < 4; ++r) {
                float v = acc[i][j][r] + bvv;
                if (rgn == 0) v *= cscale;
                pk[r] = f2h(v);
            }
            if (rgn == 2) {
                *(u16x4*)(vTout + ((size_t)(b * NH + h) * 64 + d) * SEQ + s0) = pk;
            } else {
                u16* dst = (rgn == 0) ? qP : kP;
#pragma unroll
                for (int r = 0; r < 4; ++r)
                    dst[((size_t)(b * NH + h) * SEQ + s0 + r) * DH + d] = pk[r];
            }
        }
    }
}

// ---------------- software-pipelined stage-free attention (R11, verified best) ----------------
// grid = (24 bh fast -> XCD L2 locality, 32 q-tiles of 64). Wave: all 64 q x
// its 32-key strip. Pipeline: sc(t) computed LAST iteration; per iter issue
// loads(t+1) -> exp(t) [VALU] -> QK(t+1) [MFMA pipe overlaps] -> P(t) LDS
// roundtrip -> ones+PV(t). launch_bounds(256,2): 256-reg budget, no spills.
// Single wave-private P buffer, pad 36 u16 (measured 12.8x conflict cut).

__global__ __launch_bounds__(256, 2) void attn_kernel(const u16* __restrict__ qP, const u16* __restrict__ kP,
                                                      const u16* __restrict__ vT, u16* __restrict__ attn) {
    const int tid = threadIdx.x;
    const int wid = tid >> 6;
    const int lane = tid & 63;
    const int qd = lane >> 4;
    const int l15 = lane & 15;

    const int bh = blockIdx.x;
    const int b = bh / NH, h = bh % NH;
    const int q0 = blockIdx.y * 64;

    __shared__ alignas(16) u16 smem[9216];   // 18 KB: per wave [64][36] P
    u16* ps = smem + wid * 2304;

    halfx8 aq[4][2];
#pragma unroll
    for (int jn = 0; jn < 4; ++jn)
#pragma unroll
        for (int ks = 0; ks < 2; ++ks)
            aq[jn][ks] = *(const halfx8*)(qP + (size_t)(bh * SEQ + q0 + jn * 16 + l15) * DH + ks * 32 + qd * 8);

    halfx8 ones;
#pragma unroll
    for (int j = 0; j < 8; ++j) ones[j] = (__fp16)1.0f;

    floatx4 o[4][4];
#pragma unroll
    for (int ip = 0; ip < 4; ++ip)
#pragma unroll
        for (int jn = 0; jn < 4; ++jn) o[ip][jn] = (floatx4)(0.0f);
    floatx4 lsum[4];
#pragma unroll
    for (int jn = 0; jn < 4; ++jn) lsum[jn] = (floatx4)(0.0f);

    const u16* kbase = kP + (size_t)(bh * SEQ + wid * 32 + l15) * DH + qd * 8;
    const u16* vbase = vT + (size_t)(bh * 64 + l15) * SEQ + wid * 32 + qd * 8;

    // prologue: load K(0), V(0); compute sc = QK(0)
    halfx8 akn[2][2], avc[4];
#pragma unroll
    for (int mi = 0; mi < 2; ++mi)
#pragma unroll
        for (int ks = 0; ks < 2; ++ks)
            akn[mi][ks] = *(const halfx8*)(kbase + (size_t)(mi * 16) * DH + ks * 32);
#pragma unroll
    for (int ip = 0; ip < 4; ++ip)
        avc[ip] = *(const halfx8*)(vbase + (size_t)(ip * 16) * SEQ);

    floatx4 sc[2][4];
#pragma unroll
    for (int mi = 0; mi < 2; ++mi)
#pragma unroll
        for (int jn = 0; jn < 4; ++jn) sc[mi][jn] = (floatx4)(0.0f);
#pragma unroll
    for (int ks = 0; ks < 2; ++ks)
#pragma unroll
        for (int mi = 0; mi < 2; ++mi)
#pragma unroll
            for (int jn = 0; jn < 4; ++jn)
                sc[mi][jn] = __builtin_amdgcn_mfma_f32_16x16x32_f16(akn[mi][ks], aq[jn][ks], sc[mi][jn], 0, 0, 0);

    for (int kt = 0; kt < 16; ++kt) {
        int ktn = (kt + 1) & 15;
        // loads for t+1 (wrap harmless)
        halfx8 avn[4];
#pragma unroll
        for (int mi = 0; mi < 2; ++mi)
#pragma unroll
            for (int ks = 0; ks < 2; ++ks)
                akn[mi][ks] = *(const halfx8*)(kbase + (size_t)(ktn * 128 + mi * 16) * DH + ks * 32);
#pragma unroll
        for (int ip = 0; ip < 4; ++ip)
            avn[ip] = *(const halfx8*)(vbase + (size_t)(ip * 16) * SEQ + ktn * 128);

        // exp(t) from sc (computed last iteration -> no MFMA hazard)
#pragma unroll
        for (int mi = 0; mi < 2; ++mi)
#pragma unroll
            for (int jn = 0; jn < 4; ++jn) {
                float p0 = __builtin_amdgcn_exp2f(sc[mi][jn][0]);
                float p1 = __builtin_amdgcn_exp2f(sc[mi][jn][1]);
                float p2 = __builtin_amdgcn_exp2f(sc[mi][jn][2]);
                float p3 = __builtin_amdgcn_exp2f(sc[mi][jn][3]);
                union { u16x4 u; halfx2 h[2]; } pk;
                pk.h[0] = __builtin_amdgcn_cvt_pkrtz(p0, p1);
                pk.h[1] = __builtin_amdgcn_cvt_pkrtz(p2, p3);
                *(u16x4*)(ps + (jn * 16 + l15) * 36 + mi * 16 + qd * 4) = pk.u;
            }

        // QK(t+1) on the MFMA pipe (overlaps the exp/pack VALU above)
        floatx4 scn[2][4];
#pragma unroll
        for (int mi = 0; mi < 2; ++mi)
#pragma unroll
            for (int jn = 0; jn < 4; ++jn) scn[mi][jn] = (floatx4)(0.0f);
#pragma unroll
        for (int ks = 0; ks < 2; ++ks)
#pragma unroll
            for (int mi = 0; mi < 2; ++mi)
#pragma unroll
                for (int jn = 0; jn < 4; ++jn)
                    scn[mi][jn] = __builtin_amdgcn_mfma_f32_16x16x32_f16(akn[mi][ks], aq[jn][ks], scn[mi][jn], 0, 0, 0);

        // P(t) fragments (same-wave DS write->read ordering)
        halfx8 bp[4];
#pragma unroll
        for (int jn = 0; jn < 4; ++jn) {
            union { halfx8 h8; u16x4 u4[2]; } bpu;
            bpu.u4[0] = *(const u16x4*)(ps + (jn * 16 + l15) * 36 + qd * 8);
            bpu.u4[1] = *(const u16x4*)(ps + (jn * 16 + l15) * 36 + qd * 8 + 4);
            bp[jn] = bpu.h8;
        }

#pragma unroll
        for (int jn = 0; jn < 4; ++jn)
            lsum[jn] = __builtin_amdgcn_mfma_f32_16x16x32_f16(ones, bp[jn], lsum[jn], 0, 0, 0);
#pragma unroll
        for (int ip = 0; ip < 4; ++ip)
#pragma unroll
            for (int jn = 0; jn < 4; ++jn)
                o[ip][jn] = __builtin_amdgcn_mfma_f32_16x16x32_f16(avc[ip], bp[jn], o[ip][jn], 0, 0, 0);

#pragma unroll
        for (int ip = 0; ip < 4; ++ip) avc[ip] = avn[ip];
#pragma unroll
        for (int mi = 0; mi < 2; ++mi)
#pragma unroll
            for (int jn = 0; jn < 4; ++jn) sc[mi][jn] = scn[mi][jn];
    }

    // ---- cross-wave sum through LDS (aliases P region; P is dead) ----
    float* Oacc = (float*)smem;                  // [64][68] fp32
    float* la = (float*)smem + 4352;             // [64]

    __syncthreads();
    if (wid == 0) {
#pragma unroll
        for (int jn = 0; jn < 4; ++jn) {
            int q = jn * 16 + l15;
#pragma unroll
            for (int ip = 0; ip < 4; ++ip)
                *(floatx4*)(Oacc + q * 68 + ip * 16 + qd * 4) = o[ip][jn];
            if (qd == 0) la[q] = lsum[jn][0];
        }
    }
    for (int w = 1; w < 4; ++w) {
        __syncthreads();
        if (wid == w) {
#pragma unroll
            for (int jn = 0; jn < 4; ++jn) {
                int q = jn * 16 + l15;
#pragma unroll
                for (int ip = 0; ip < 4; ++ip) {
                    float* p = Oacc + q * 68 + ip * 16 + qd * 4;
                    *(floatx4*)p = *(floatx4*)p + o[ip][jn];
                }
                if (qd == 0) la[q] += lsum[jn][0];
            }
        }
    }
    __syncthreads();

    {
        int q = tid >> 2, d0 = (tid & 3) * 16;
        float inv = __builtin_amdgcn_rcpf(la[q]);
        const float* op = Oacc + q * 68 + d0;
        u16x8 pk0, pk1;
#pragma unroll
        for (int r = 0; r < 8; ++r) pk0[r] = f2h(op[r] * inv);
#pragma unroll
        for (int r = 0; r < 8; ++r) pk1[r] = f2h(op[8 + r] * inv);
        u16* dst = attn + (size_t)(b * SEQ + q0 + q) * D_MODEL + h * DH + d0;
        *(u16x8*)dst = pk0;
        *(u16x8*)(dst + 8) = pk1;
    }
}

// ---------------- out GEMM: C[4096][768] = A * WoT^T + bias (fp32 out) ----------------
// 64x64 tile (768 blocks, 3/CU), BK=64, 4 waves each 32x32.

__global__ __launch_bounds__(256) void gemm_out(const u16* __restrict__ A, const u16* __restrict__ Bt,
                                                const float* __restrict__ bias, float* __restrict__ Cout) {
    const int tid = threadIdx.x;
    const int wid = tid >> 6;
    const int lane = tid & 63;
    const int qd = lane >> 4;
    const int l15 = lane & 15;

    const int tn = blockIdx.x * 64;
    const int tm = blockIdx.y * 64;
    const int wm = (wid >> 1) * 32;
    const int wn = (wid & 1) * 32;

    __shared__ alignas(16) u16 As[64 * 64];
    __shared__ alignas(16) u16 Bs[64 * 64];

    floatx4 acc[2][2];
#pragma unroll
    for (int i = 0; i < 2; ++i)
#pragma unroll
        for (int j = 0; j < 2; ++j) acc[i][j] = (floatx4)(0.0f);

    const u16* Ag[2];
    const u16* Bg[2];
#pragma unroll
    for (int rd = 0; rd < 2; ++rd) {
        int s = rd * 256 + tid;
        int r = s >> 3, bl = (s & 7) ^ (r & 7);
        Ag[rd] = A + (size_t)(tm + r) * 768 + bl * 8;
        Bg[rd] = Bt + (size_t)(tn + r) * 768 + bl * 8;
    }

    for (int kb = 0; kb < 768; kb += 64) {
        __syncthreads();
#pragma unroll
        for (int rd = 0; rd < 2; ++rd) {
            gload_lds16(Ag[rd] + kb, As + (size_t)(rd * 256 + tid) * 8);
            gload_lds16(Bg[rd] + kb, Bs + (size_t)(rd * 256 + tid) * 8);
        }
        __syncthreads();

#pragma unroll
        for (int ks = 0; ks < 2; ++ks) {
            halfx8 af[2], bf[2];
#pragma unroll
            for (int i = 0; i < 2; ++i) {
                int r = wm + i * 16 + l15;
                af[i] = *(const halfx8*)(As + r * 64 + (((ks * 4 + qd) ^ (r & 7)) * 8));
                int r2 = wn + i * 16 + l15;
                bf[i] = *(const halfx8*)(Bs + r2 * 64 + (((ks * 4 + qd) ^ (r2 & 7)) * 8));
            }
#pragma unroll
            for (int i = 0; i < 2; ++i)
#pragma unroll
                for (int j = 0; j < 2; ++j)
                    acc[i][j] = __builtin_amdgcn_mfma_f32_16x16x32_f16(af[i], bf[j], acc[i][j], 0, 0, 0);
        }
    }

#pragma unroll
    for (int j = 0; j < 2; ++j) {
        int col = tn + wn + j * 16 + l15;
        float bv = bias[col];
#pragma unroll
        for (int i = 0; i < 2; ++i) {
            int row0 = tm + wm + i * 16 + qd * 4;
#pragma unroll
            for (int r = 0; r < 4; ++r)
                Cout[(size_t)(row0 + r) * 768 + col] = acc[i][j][r] + bv;
        }
    }
}

// ---------------- launch ----------------

extern "C" void kernel_launch(void* const* d_in, const int* in_sizes, int n_in,
                              void* d_out, int out_size, void* d_ws, size_t ws_size,
                              hipStream_t stream) {
    const float* x  = (const float*)d_in[0];
    const float* Wq = (const float*)d_in[1];
    const float* bq = (const float*)d_in[2];
    const float* Wk = (const float*)d_in[3];
    const float* bk = (const float*)d_in[4];
    const float* Wv = (const float*)d_in[5];
    const float* bv = (const float*)d_in[6];
    const float* Wo = (const float*)d_in[7];
    const float* bo = (const float*)d_in[8];

    char* ws = (char*)d_ws;
    size_t off = 0;
    auto take = [&](size_t bytes) -> char* {
        char* p = ws + off;
        off += (bytes + 255) & ~(size_t)255;
        return p;
    };
    u16* WqkvT = (u16*)take((size_t)DQKV * D_MODEL * 2);
    u16* WoT   = (u16*)take((size_t)D_MODEL * D_MODEL * 2);
    u16* qP    = (u16*)take((size_t)MTOK * D_MODEL * 2);
    u16* kP    = (u16*)take((size_t)MTOK * D_MODEL * 2);
    u16* vTb   = (u16*)take((size_t)BATCH * NH * DH * SEQ * 2);
    u16* attn  = (u16*)take((size_t)MTOK * D_MODEL * 2);

    wprep_kernel<<<576, 256, 0, stream>>>(Wq, Wk, Wv, Wo, WqkvT, WoT);
    gemm_qkv<<<dim3(DQKV / 128, MTOK / 64), 256, 0, stream>>>(x, WqkvT, bq, bk, bv, qP, kP, vTb);
    attn_kernel<<<dim3(BATCH * NH, SEQ / 64), 256, 0, stream>>>(qP, kP, vTb, attn);
    gemm_out<<<dim3(D_MODEL / 64, MTOK / 64), 256, 0, stream>>>(attn, WoT, bo, (float*)d_out);
}